// Round 10
// baseline (246.075 us; speedup 1.0000x reference)
//
#include <hip/hip_runtime.h>
#include <hip/hip_bf16.h>
#include <math.h>

#define BB   8
#define LL   200
#define MM   4
#define SS   100
#define DD   128
#define FF   4
#define NT   300
#define ROWS (BB*LL)   // 1600
#define JT2  64        // j per tprep block

// stage1 block ranges
#define NB_TR  128
#define NB_TP  500     // 100 s x 5 j-chunks of 64
#define NB_AT  800     // 3200 (row,which) tasks / 4 waves per block
// stage2 block ranges
#define NB_PJ  400     // proj: 4 rows/block
#define NB_FH  1600    // fh: 2 tasks/block

__device__ __forceinline__ float sigf(float x){ return 1.f/(1.f+expf(-x)); }

// bf16 round-to-nearest-even pack/unpack (T is stored bf16 to halve gather BW)
__device__ __forceinline__ unsigned short f2bf(float x){
    unsigned int u = __float_as_uint(x);
    unsigned int r = (u + 0x7FFFu + ((u >> 16) & 1u)) >> 16;
    return (unsigned short)r;
}
__device__ __forceinline__ float bf2f(unsigned short v){
    return __uint_as_float(((unsigned int)v) << 16);
}

// ===========================================================================
// STAGE 1: transpose (4 weight mats -> [128][512]) | tprep | attn
// ===========================================================================
__global__ void __launch_bounds__(256) k_stage1(
    // transpose
    const float* __restrict__ wih_in, const float* __restrict__ wih_fg,
    const float* __restrict__ whh_in, const float* __restrict__ whh_fg,
    float* __restrict__ wT_in, float* __restrict__ wT_fg,
    float* __restrict__ whhT_in, float* __restrict__ whhT_fg,
    // tprep
    const float* __restrict__ Es, const float* __restrict__ Wc,
    const float* __restrict__ Wp, unsigned short* __restrict__ T16,
    // attn
    const int* __restrict__ q,  const int* __restrict__ c,
    const int* __restrict__ sq, const int* __restrict__ sc,
    const float* __restrict__ Eq,
    float* __restrict__ att0, float* __restrict__ att1)
{
    __shared__ float WcL[JT2][128];   // 32 KB, tprep branch only
    int b   = blockIdx.x;
    int tid = threadIdx.x;

    if (b < NB_TR) {
        // ---- transpose: dst[k*512+g] = src[g*128+k], 4 mats x 65536 ----
        for (int e = b*256 + tid; e < 4*65536; e += NB_TR*256) {
            int mat = e >> 16, o = e & 65535;
            int k = o >> 9, g = o & 511;
            const float* src = (mat==0)?wih_in:(mat==1)?wih_fg:(mat==2)?whh_in:whh_fg;
            float*       dst = (mat==0)?wT_in:(mat==1)?wT_fg:(mat==2)?whhT_in:whhT_fg;
            dst[o] = src[g*128 + k];
        }
        return;
    }
    if (b < NB_TR + NB_TP) {
        // ---- tprep: T[s][j][t] = sum_d Wc[j,d]*Es[s,d]*Wp[s*428+d,t] + Wp[s*428+128+j,t]
        // thread owns t-quad (float4) x 8 j; per-4d: 4 global float4 + 8 LDS b128 + 128 FMA
        int bb2 = b - NB_TR;
        int s  = bb2 / 5;
        int jc = bb2 - s*5;
        int j0 = jc * JT2;
        const float* es = Es + s*128;
        for (int idx = tid; idx < JT2*128; idx += 256) {
            int jj = idx >> 7, d = idx & 127;
            int j = j0 + jj;
            WcL[jj][d] = (j < NT) ? Wc[j*128 + d] * es[d] : 0.f;
        }
        __syncthreads();

        const float*  wp  = Wp + (size_t)s*428*128;
        const float4* wp4 = (const float4*)wp;          // row d = 32 float4
        int tq = tid & 31;                // owns t = 4*tq .. 4*tq+3
        int jg = tid >> 5;                // 0..7, owns 8 j's
        float4 acc[8];
        #pragma unroll
        for (int j = 0; j < 8; j++) acc[j] = make_float4(0.f,0.f,0.f,0.f);

        for (int d4 = 0; d4 < 128; d4 += 4) {
            float4 wv[4];
            #pragma unroll
            for (int u = 0; u < 4; u++) wv[u] = wp4[(d4+u)*32 + tq];
            float4 wc[8];
            #pragma unroll
            for (int j = 0; j < 8; j++)
                wc[j] = *(const float4*)&WcL[jg*8 + j][d4];   // b128, wave-broadcast
            #pragma unroll
            for (int u = 0; u < 4; u++) {
                float4 wpv = wv[u];
                #pragma unroll
                for (int j = 0; j < 8; j++) {
                    float w = (u==0)?wc[j].x:(u==1)?wc[j].y:(u==2)?wc[j].z:wc[j].w;
                    acc[j].x += w * wpv.x;
                    acc[j].y += w * wpv.y;
                    acc[j].z += w * wpv.z;
                    acc[j].w += w * wpv.w;
                }
            }
        }

        const float4* wpe4 = (const float4*)(wp + 128*128);   // rows 128..427
        ushort4* T4 = (ushort4*)T16;
        #pragma unroll
        for (int j = 0; j < 8; j++) {
            int jj = j0 + jg*8 + j;
            if (jj < NT) {
                float4 bv = wpe4[(size_t)jj*32 + tq];
                ushort4 st;
                st.x = f2bf(acc[j].x + bv.x);
                st.y = f2bf(acc[j].y + bv.y);
                st.z = f2bf(acc[j].z + bv.z);
                st.w = f2bf(acc[j].w + bv.w);
                T4[((size_t)s*NT + jj)*32 + tq] = st;
            }
        }
        return;
    }
    // ---- attn: 4 waves/block, each wave = one (row,which) task ----
    {
        int wv   = tid >> 6;
        int lane = tid & 63;
        int task = (b - NB_TR - NB_TP)*4 + wv;   // 0..3199
        int row   = task >> 1;
        int which = task & 1;
        const int* qq = which ? sq : q;
        const int* cc = which ? sc : c;
        float* out = which ? att1 : att0;

        size_t qb = (size_t)qq[row]*128;
        float eq0 = Eq[qb + lane];
        float eq1 = Eq[qb + 64 + lane];
        int   s[4];
        float es0[4], es1[4], d[4];
        #pragma unroll
        for (int m = 0; m < 4; m++) {
            s[m]  = cc[row*4 + m];
            es0[m] = (s[m] >= 0) ? Es[s[m]*128 + lane]      : 0.f;
            es1[m] = (s[m] >= 0) ? Es[s[m]*128 + 64 + lane] : 0.f;
            d[m] = eq0*es0[m] + eq1*es1[m];
        }
        #pragma unroll
        for (int off = 32; off > 0; off >>= 1) {
            #pragma unroll
            for (int m = 0; m < 4; m++) d[m] += __shfl_xor(d[m], off);
        }
        const float inv = 0.08838834764831845f;   // 1/sqrt(128)
        int   nact = 0;
        float mx = 0.f;
        #pragma unroll
        for (int m = 0; m < 4; m++) {
            d[m] *= inv;
            if (s[m] >= 0) { nact++; mx = fmaxf(mx, d[m]); }
        }
        float Z = (float)(SS - nact) * expf(-mx);
        float w[4];
        #pragma unroll
        for (int m = 0; m < 4; m++) {
            w[m] = (s[m] >= 0) ? expf(d[m] - mx) : 0.f;
            Z += w[m];
        }
        float a0 = 0.f, a1 = 0.f;
        #pragma unroll
        for (int m = 0; m < 4; m++) {
            float ww = w[m]/Z;
            a0 += ww * es0[m];
            a1 += ww * es1[m];
        }
        out[row*128 + lane]      = a0;
        out[row*128 + 64 + lane] = a1;
    }
}

// ===========================================================================
// STAGE 2: proj (xemb + shiftx) | fh (both forget gathers, bf16 T)
// ===========================================================================
__global__ void __launch_bounds__(256) k_stage2(
    // proj
    const int* __restrict__ q, const int* __restrict__ r, const int* __restrict__ sq,
    const float* __restrict__ Eq, const float* __restrict__ Er,
    const float* __restrict__ att, const float* __restrict__ satt,
    const float* __restrict__ Wl2, const float* __restrict__ bl2,
    const float* __restrict__ Wl3, const float* __restrict__ bl3,
    float* __restrict__ xemb, float* __restrict__ shiftx,
    // fh
    const int* __restrict__ c,  const int* __restrict__ rg,
    const int* __restrict__ pc, const int* __restrict__ ac,
    const int* __restrict__ sc, const int* __restrict__ srg,
    const int* __restrict__ spc,const int* __restrict__ sac,
    const unsigned short* __restrict__ T16, const float* __restrict__ bpre,
    float* __restrict__ fh0, float* __restrict__ fh1)
{
    __shared__ float xs1[4][384];
    __shared__ float xs2[4][256];
    __shared__ float part[2][4][128];
    int b   = blockIdx.x;
    int tid = threadIdx.x;

    if (b < NB_PJ) {
        // ---- proj: 4 rows/block ----
        int r0 = b*4;
        for (int e = tid; e < 4*384; e += 256) {
            int i = e / 384, pos = e - i*384;
            int row = r0 + i;
            float v;
            if (pos < 128)      v = Eq[(size_t)q[row]*128 + pos];
            else if (pos < 256) v = Er[r[row]*128 + (pos-128)];
            else                v = att[row*128 + (pos-256)];
            xs1[i][pos] = v;
        }
        for (int e = tid; e < 4*256; e += 256) {
            int i = e >> 8, pos = e & 255;
            int row = r0 + i;
            xs2[i][pos] = (pos < 128) ? Eq[(size_t)sq[row]*128 + pos]
                                      : satt[row*128 + (pos-128)];
        }
        __syncthreads();

        int kg  = tid >> 7;
        int col = tid & 127;
        // l2: K=384, halves of 192
        {
            float acc[4];
            #pragma unroll
            for (int i = 0; i < 4; i++) acc[i] = 0.f;
            int k0 = kg*192;
            for (int kb = 0; kb < 192; kb += 8) {
                float wb[8];
                #pragma unroll
                for (int u = 0; u < 8; u++) wb[u] = Wl2[(k0+kb+u)*128 + col];
                #pragma unroll
                for (int u = 0; u < 8; u++) {
                    #pragma unroll
                    for (int i = 0; i < 4; i++) acc[i] += xs1[i][k0+kb+u]*wb[u];
                }
            }
            #pragma unroll
            for (int i = 0; i < 4; i++) part[kg][i][col] = acc[i];
        }
        __syncthreads();
        for (int e = tid; e < 512; e += 256) {
            int i = e >> 7, cc2 = e & 127;
            xemb[(r0+i)*128 + cc2] = bl2[cc2] + part[0][i][cc2] + part[1][i][cc2];
        }
        __syncthreads();
        // l3: K=256, halves of 128
        {
            float acc[4];
            #pragma unroll
            for (int i = 0; i < 4; i++) acc[i] = 0.f;
            int k0 = kg*128;
            for (int kb = 0; kb < 128; kb += 8) {
                float wb[8];
                #pragma unroll
                for (int u = 0; u < 8; u++) wb[u] = Wl3[(k0+kb+u)*128 + col];
                #pragma unroll
                for (int u = 0; u < 8; u++) {
                    #pragma unroll
                    for (int i = 0; i < 4; i++) acc[i] += xs2[i][k0+kb+u]*wb[u];
                }
            }
            #pragma unroll
            for (int i = 0; i < 4; i++) part[kg][i][col] = acc[i];
        }
        __syncthreads();
        for (int e = tid; e < 512; e += 256) {
            int i = e >> 7, cc2 = e & 127;
            shiftx[(r0+i)*128 + cc2] = bl3[cc2] + part[0][i][cc2] + part[1][i][cc2];
        }
        return;
    }
    // ---- fh: 2 tasks/block (128 threads each), bf16 T gather ----
    {
        int u     = (b - NB_PJ)*2 + (tid >> 7);   // 0..3199
        int which = u & 1;
        int row   = u >> 1;
        int t     = tid & 127;
        const int* C  = which ? sc  : c;
        const int* RG = which ? srg : rg;
        const int* PC = which ? spc : pc;
        const int* AC = which ? sac : ac;
        float* out = which ? fh1 : fh0;

        float acc = bpre[t];
        for (int m = 0; m < 4; m++) {
            int s = C[row*4 + m];
            if (s < 0) continue;
            int rgv = RG[row*4 + m];
            const unsigned short* Ts = T16 + (size_t)s*NT*128;
            #pragma unroll
            for (int f = 0; f < 4; f++) {
                int j1 = f*25 + rgv;
                int j2 = 100 + f*25 + PC[(row*4+m)*4 + f];
                int j3 = 200 + f*25 + AC[(row*4+m)*4 + f];
                acc += bf2f(Ts[j1*128 + t]) + bf2f(Ts[j2*128 + t]) + bf2f(Ts[j3*128 + t]);
            }
        }
        out[row*128 + t] = acc;
    }
}

// ===========================================================================
// LSTM with fused gates. grid (200, 2), 512 threads, ONE row per block.
// Thread owns gate col p = tid; whh col held in 128 VGPRs; h broadcast LDS.
// ===========================================================================
__global__ void __launch_bounds__(512) k_lstm(
    const float* __restrict__ xemb, const float* __restrict__ fh,
    const float* __restrict__ wT_in, const float* __restrict__ wT_fg,
    const float* __restrict__ whhT_in, const float* __restrict__ whhT_fg,
    const float* __restrict__ bih_in, const float* __restrict__ bhh_in,
    const float* __restrict__ bih_fg, const float* __restrict__ bhh_fg,
    float* __restrict__ h_in_out, float* __restrict__ h_fg_out)
{
    int which = blockIdx.y;
    const float* X  = which ? fh      : xemb;
    const float* WI = which ? wT_fg   : wT_in;
    const float* WH = which ? whhT_fg : whhT_in;
    const float* B1 = which ? bih_fg  : bih_in;
    const float* B2 = which ? bhh_fg  : bhh_in;
    float* OUT = which ? h_fg_out : h_in_out;

    int l0  = blockIdx.x;          // row 0..199
    int tid = threadIdx.x;         // gate col p

    __shared__ float xr[8][128];   // x for all 8 steps
    __shared__ float gb[8][512];   // x-gates for all steps
    __shared__ float h[128], cs[128], gl[512];

    for (int e = tid; e < 1024; e += 512) {
        int t = e >> 7, d = e & 127;
        xr[t][d] = X[(size_t)(t*200 + l0)*128 + d];
    }
    if (tid < 128) { h[tid] = 0.f; cs[tid] = 0.f; }
    __syncthreads();

    // gates: gb[t][p] = bb + sum_k xr[t][k] * WI[k*512+p]
    float bb = B1[tid] + B2[tid];
    {
        float a[8];
        #pragma unroll
        for (int i = 0; i < 8; i++) a[i] = bb;
        for (int kb = 0; kb < 128; kb += 8) {
            float wv[8];
            #pragma unroll
            for (int u = 0; u < 8; u++) wv[u] = WI[(kb+u)*512 + tid];
            #pragma unroll
            for (int u = 0; u < 8; u++) {
                #pragma unroll
                for (int i = 0; i < 8; i++) a[i] += xr[i][kb+u]*wv[u];
            }
        }
        #pragma unroll
        for (int i = 0; i < 8; i++) gb[i][tid] = a[i];
    }

    // whh column -> registers (static indices => VGPRs)
    float w[128];
    #pragma unroll
    for (int k = 0; k < 128; k++) w[k] = WH[k*512 + tid];
    __syncthreads();

    // recurrence over 8 steps; no global loads inside
    for (int t = 0; t < 8; t++) {
        float a0 = gb[t][tid];
        #pragma unroll
        for (int k = 0; k < 128; k++) a0 += h[k]*w[k];   // LDS broadcast
        gl[tid] = a0;
        __syncthreads();
        if (tid < 128) {
            float gi = gl[tid], gf = gl[128+tid], gg = gl[256+tid], go = gl[384+tid];
            float cn = sigf(gf)*cs[tid] + sigf(gi)*tanhf(gg);
            float hn = sigf(go)*tanhf(cn);
            cs[tid] = cn;
            h[tid]  = hn;
            OUT[(size_t)(t*200 + l0)*128 + tid] = hn;
        }
        __syncthreads();
    }
}

// ===========================================================================
// FINAL: x1=relu([shiftx|h_in]@W4+b4); x2=relu([fh1|h_fg]@W5+b5);
// y=sigmoid([x1|x2]@W3+b3). 4 rows/block, 400 blocks, 256 thr.
// ===========================================================================
__global__ void __launch_bounds__(256) k_final(
    const float* __restrict__ shiftx, const float* __restrict__ h_in,
    const float* __restrict__ fh_shift, const float* __restrict__ h_fg,
    const float* __restrict__ Wfc4, const float* __restrict__ bfc4,
    const float* __restrict__ Wfc5, const float* __restrict__ bfc5,
    const float* __restrict__ Wfc3, const float* __restrict__ bfc3,
    float* __restrict__ out)
{
    int r0  = blockIdx.x * 4;
    int tid = threadIdx.x;
    int kg  = tid >> 7;
    int col = tid & 127;
    __shared__ float xa[4][256], xb[4][256];
    __shared__ float part[2][4][128];

    for (int e = tid; e < 4*256; e += 256) {
        int i = e >> 8, pos = e & 255;
        int row = r0 + i;
        xa[i][pos] = (pos < 128) ? shiftx[row*128 + pos]   : h_in[row*128 + pos-128];
        xb[i][pos] = (pos < 128) ? fh_shift[row*128 + pos] : h_fg[row*128 + pos-128];
    }
    __syncthreads();

    float acc4[4], acc5[4];
    #pragma unroll
    for (int i = 0; i < 4; i++) { acc4[i] = 0.f; acc5[i] = 0.f; }
    int k0 = kg * 128;
    for (int kb = 0; kb < 128; kb += 8) {
        float w4[8], w5[8];
        #pragma unroll
        for (int u = 0; u < 8; u++) {
            w4[u] = Wfc4[(k0+kb+u)*128 + col];
            w5[u] = Wfc5[(k0+kb+u)*128 + col];
        }
        #pragma unroll
        for (int u = 0; u < 8; u++) {
            int k = k0 + kb + u;
            #pragma unroll
            for (int i = 0; i < 4; i++) {
                acc4[i] += xa[i][k] * w4[u];
                acc5[i] += xb[i][k] * w5[u];
            }
        }
    }

    #pragma unroll
    for (int i = 0; i < 4; i++) part[kg][i][col] = acc4[i];
    __syncthreads();
    float x1r[2];
    #pragma unroll
    for (int j = 0; j < 2; j++) {
        int e = tid + 256*j;
        int i = e >> 7, cc2 = e & 127;
        x1r[j] = fmaxf(part[0][i][cc2] + part[1][i][cc2] + bfc4[cc2], 0.f);
    }
    __syncthreads();
    #pragma unroll
    for (int i = 0; i < 4; i++) part[kg][i][col] = acc5[i];
    __syncthreads();
    float x2r[2];
    #pragma unroll
    for (int j = 0; j < 2; j++) {
        int e = tid + 256*j;
        int i = e >> 7, cc2 = e & 127;
        x2r[j] = fmaxf(part[0][i][cc2] + part[1][i][cc2] + bfc5[cc2], 0.f);
    }
    __syncthreads();

    // fc3 contributions; reuse part[0] as cont[4][128]
    float* cont = &part[0][0][0];
    #pragma unroll
    for (int j = 0; j < 2; j++) {
        int e = tid + 256*j;
        int i = e >> 7, cc2 = e & 127;
        cont[i*128 + cc2] = x1r[j]*Wfc3[cc2] + x2r[j]*Wfc3[128 + cc2];
    }
    __syncthreads();
    int wv = tid >> 6, lane = tid & 63;      // wave wv handles row wv
    float sum = cont[wv*128 + lane] + cont[wv*128 + lane + 64];
    #pragma unroll
    for (int off = 32; off > 0; off >>= 1) sum += __shfl_xor(sum, off);
    if (lane == 0) out[r0 + wv] = 1.f/(1.f + expf(-(sum + bfc3[0])));
}

// ---------------------------------------------------------------------------
extern "C" void kernel_launch(void* const* d_in, const int* in_sizes, int n_in,
                              void* d_out, int out_size, void* d_ws, size_t ws_size,
                              hipStream_t stream)
{
    const int*   q      = (const int*)d_in[0];
    const int*   c      = (const int*)d_in[1];
    const int*   sq     = (const int*)d_in[2];
    const int*   sc     = (const int*)d_in[3];
    const int*   r      = (const int*)d_in[4];
    const int*   rg     = (const int*)d_in[5];
    const int*   pc     = (const int*)d_in[6];
    const int*   ac     = (const int*)d_in[7];
    const int*   srg    = (const int*)d_in[8];
    const int*   spc    = (const int*)d_in[9];
    const int*   sac    = (const int*)d_in[10];
    const float* Es     = (const float*)d_in[11];
    const float* Eq     = (const float*)d_in[12];
    const float* Er     = (const float*)d_in[13];
    const float* wih_in = (const float*)d_in[14];
    const float* whh_in = (const float*)d_in[15];
    const float* bih_in = (const float*)d_in[16];
    const float* bhh_in = (const float*)d_in[17];
    const float* wih_fg = (const float*)d_in[18];
    const float* whh_fg = (const float*)d_in[19];
    const float* bih_fg = (const float*)d_in[20];
    const float* bhh_fg = (const float*)d_in[21];
    const float* Wl2    = (const float*)d_in[22];
    const float* bl2    = (const float*)d_in[23];
    const float* Wl3    = (const float*)d_in[24];
    const float* bl3    = (const float*)d_in[25];
    const float* Wfc3   = (const float*)d_in[26];
    const float* bfc3   = (const float*)d_in[27];
    const float* Wfc4   = (const float*)d_in[28];
    const float* bfc4   = (const float*)d_in[29];
    const float* Wfc5   = (const float*)d_in[30];
    const float* bfc5   = (const float*)d_in[31];
    const float* Wc     = (const float*)d_in[32];
    const float* Wp     = (const float*)d_in[33];
    const float* bpre   = (const float*)d_in[34];

    float* W = (float*)d_ws;
    unsigned short* T16 = (unsigned short*)W;  W += 100*NT*128/2;   // bf16 T: 7.68 MB
    float* att     = W;  W += ROWS*128;
    float* satt    = W;  W += ROWS*128;
    float* xemb    = W;  W += ROWS*128;
    float* shiftx  = W;  W += ROWS*128;
    float* fh0     = W;  W += ROWS*128;
    float* fh1     = W;  W += ROWS*128;
    float* wT_in   = W;  W += 512*128;
    float* wT_fg   = W;  W += 512*128;
    float* whhT_in = W;  W += 512*128;
    float* whhT_fg = W;  W += 512*128;
    float* h_in    = W;  W += ROWS*128;
    float* h_fg    = W;  W += ROWS*128;

    hipLaunchKernelGGL(k_stage1, dim3(NB_TR + NB_TP + NB_AT), dim3(256), 0, stream,
        wih_in, wih_fg, whh_in, whh_fg, wT_in, wT_fg, whhT_in, whhT_fg,
        Es, Wc, Wp, T16,
        q, c, sq, sc, Eq, att, satt);

    hipLaunchKernelGGL(k_stage2, dim3(NB_PJ + NB_FH), dim3(256), 0, stream,
        q, r, sq, Eq, Er, att, satt, Wl2, bl2, Wl3, bl3, xemb, shiftx,
        c, rg, pc, ac, sc, srg, spc, sac, T16, bpre, fh0, fh1);

    hipLaunchKernelGGL(k_lstm, dim3(200, 2), dim3(512), 0, stream,
        xemb, fh0, wT_in, wT_fg, whhT_in, whhT_fg,
        bih_in, bhh_in, bih_fg, bhh_fg, h_in, h_fg);

    hipLaunchKernelGGL(k_final, dim3(400), dim3(256), 0, stream,
        shiftx, h_in, fh1, h_fg, Wfc4, bfc4, Wfc5, bfc5, Wfc3, bfc3, (float*)d_out);
}

// Round 11
// 246.031 us; speedup vs baseline: 1.0002x; 1.0002x over previous
//
#include <hip/hip_runtime.h>
#include <hip/hip_bf16.h>
#include <math.h>

#define BB   8
#define LL   200
#define MM   4
#define SS   100
#define DD   128
#define FF   4
#define NT   300
#define ROWS (BB*LL)   // 1600
#define JT2  64        // j per tprep block

// stage1 block ranges
#define NB_TR  128
#define NB_TP  500     // 100 s x 5 j-chunks of 64
#define NB_AT  800     // 3200 (row,which) tasks / 4 waves per block
// stage2 block ranges
#define NB_PJ  400     // proj: 4 rows/block
#define NB_FH  1600    // fh: 2 tasks/block

__device__ __forceinline__ float sigf(float x){ return 1.f/(1.f+expf(-x)); }

// bf16 round-to-nearest-even pack/unpack (T is stored bf16 to halve gather BW)
__device__ __forceinline__ unsigned short f2bf(float x){
    unsigned int u = __float_as_uint(x);
    unsigned int r = (u + 0x7FFFu + ((u >> 16) & 1u)) >> 16;
    return (unsigned short)r;
}
__device__ __forceinline__ float bf2f(unsigned short v){
    return __uint_as_float(((unsigned int)v) << 16);
}
// wave-uniform broadcast of lane k's value (VALU v_readlane, no LDS pipe)
__device__ __forceinline__ float rdlane(float v, int k){
    return __int_as_float(__builtin_amdgcn_readlane(__float_as_int(v), k));
}

// ===========================================================================
// STAGE 1: transpose (4 weight mats -> [128][512]) | tprep | attn
// ===========================================================================
__global__ void __launch_bounds__(256) k_stage1(
    // transpose
    const float* __restrict__ wih_in, const float* __restrict__ wih_fg,
    const float* __restrict__ whh_in, const float* __restrict__ whh_fg,
    float* __restrict__ wT_in, float* __restrict__ wT_fg,
    float* __restrict__ whhT_in, float* __restrict__ whhT_fg,
    // tprep
    const float* __restrict__ Es, const float* __restrict__ Wc,
    const float* __restrict__ Wp, unsigned short* __restrict__ T16,
    // attn
    const int* __restrict__ q,  const int* __restrict__ c,
    const int* __restrict__ sq, const int* __restrict__ sc,
    const float* __restrict__ Eq,
    float* __restrict__ att0, float* __restrict__ att1)
{
    __shared__ float WcL[JT2][128];   // 32 KB, tprep branch only
    int b   = blockIdx.x;
    int tid = threadIdx.x;

    if (b < NB_TR) {
        // ---- transpose: dst[k*512+g] = src[g*128+k], 4 mats x 65536 ----
        for (int e = b*256 + tid; e < 4*65536; e += NB_TR*256) {
            int mat = e >> 16, o = e & 65535;
            int k = o >> 9, g = o & 511;
            const float* src = (mat==0)?wih_in:(mat==1)?wih_fg:(mat==2)?whh_in:whh_fg;
            float*       dst = (mat==0)?wT_in:(mat==1)?wT_fg:(mat==2)?whhT_in:whhT_fg;
            dst[o] = src[g*128 + k];
        }
        return;
    }
    if (b < NB_TR + NB_TP) {
        // ---- tprep: T[s][j][t] = sum_d Wc[j,d]*Es[s,d]*Wp[s*428+d,t] + Wp[s*428+128+j,t]
        int bb2 = b - NB_TR;
        int s  = bb2 / 5;
        int jc = bb2 - s*5;
        int j0 = jc * JT2;
        const float* es = Es + s*128;
        for (int idx = tid; idx < JT2*128; idx += 256) {
            int jj = idx >> 7, d = idx & 127;
            int j = j0 + jj;
            WcL[jj][d] = (j < NT) ? Wc[j*128 + d] * es[d] : 0.f;
        }
        __syncthreads();

        const float*  wp  = Wp + (size_t)s*428*128;
        const float4* wp4 = (const float4*)wp;          // row d = 32 float4
        int tq = tid & 31;                // owns t = 4*tq .. 4*tq+3
        int jg = tid >> 5;                // 0..7, owns 8 j's
        float4 acc[8];
        #pragma unroll
        for (int j = 0; j < 8; j++) acc[j] = make_float4(0.f,0.f,0.f,0.f);

        for (int d4 = 0; d4 < 128; d4 += 4) {
            float4 wv[4];
            #pragma unroll
            for (int u = 0; u < 4; u++) wv[u] = wp4[(d4+u)*32 + tq];
            float4 wc[8];
            #pragma unroll
            for (int j = 0; j < 8; j++)
                wc[j] = *(const float4*)&WcL[jg*8 + j][d4];   // b128, wave-broadcast
            #pragma unroll
            for (int u = 0; u < 4; u++) {
                float4 wpv = wv[u];
                #pragma unroll
                for (int j = 0; j < 8; j++) {
                    float w = (u==0)?wc[j].x:(u==1)?wc[j].y:(u==2)?wc[j].z:wc[j].w;
                    acc[j].x += w * wpv.x;
                    acc[j].y += w * wpv.y;
                    acc[j].z += w * wpv.z;
                    acc[j].w += w * wpv.w;
                }
            }
        }

        const float4* wpe4 = (const float4*)(wp + 128*128);   // rows 128..427
        ushort4* T4 = (ushort4*)T16;
        #pragma unroll
        for (int j = 0; j < 8; j++) {
            int jj = j0 + jg*8 + j;
            if (jj < NT) {
                float4 bv = wpe4[(size_t)jj*32 + tq];
                ushort4 st;
                st.x = f2bf(acc[j].x + bv.x);
                st.y = f2bf(acc[j].y + bv.y);
                st.z = f2bf(acc[j].z + bv.z);
                st.w = f2bf(acc[j].w + bv.w);
                T4[((size_t)s*NT + jj)*32 + tq] = st;
            }
        }
        return;
    }
    // ---- attn: 4 waves/block, each wave = one (row,which) task ----
    {
        int wv   = tid >> 6;
        int lane = tid & 63;
        int task = (b - NB_TR - NB_TP)*4 + wv;   // 0..3199
        int row   = task >> 1;
        int which = task & 1;
        const int* qq = which ? sq : q;
        const int* cc = which ? sc : c;
        float* out = which ? att1 : att0;

        size_t qb = (size_t)qq[row]*128;
        float eq0 = Eq[qb + lane];
        float eq1 = Eq[qb + 64 + lane];
        int   s[4];
        float es0[4], es1[4], d[4];
        #pragma unroll
        for (int m = 0; m < 4; m++) {
            s[m]  = cc[row*4 + m];
            es0[m] = (s[m] >= 0) ? Es[s[m]*128 + lane]      : 0.f;
            es1[m] = (s[m] >= 0) ? Es[s[m]*128 + 64 + lane] : 0.f;
            d[m] = eq0*es0[m] + eq1*es1[m];
        }
        #pragma unroll
        for (int off = 32; off > 0; off >>= 1) {
            #pragma unroll
            for (int m = 0; m < 4; m++) d[m] += __shfl_xor(d[m], off);
        }
        const float inv = 0.08838834764831845f;   // 1/sqrt(128)
        int   nact = 0;
        float mx = 0.f;
        #pragma unroll
        for (int m = 0; m < 4; m++) {
            d[m] *= inv;
            if (s[m] >= 0) { nact++; mx = fmaxf(mx, d[m]); }
        }
        float Z = (float)(SS - nact) * expf(-mx);
        float w[4];
        #pragma unroll
        for (int m = 0; m < 4; m++) {
            w[m] = (s[m] >= 0) ? expf(d[m] - mx) : 0.f;
            Z += w[m];
        }
        float a0 = 0.f, a1 = 0.f;
        #pragma unroll
        for (int m = 0; m < 4; m++) {
            float ww = w[m]/Z;
            a0 += ww * es0[m];
            a1 += ww * es1[m];
        }
        out[row*128 + lane]      = a0;
        out[row*128 + 64 + lane] = a1;
    }
}

// ===========================================================================
// STAGE 2: proj (xemb + shiftx) | fh (both forget gathers, bf16 T)
// ===========================================================================
__global__ void __launch_bounds__(256) k_stage2(
    // proj
    const int* __restrict__ q, const int* __restrict__ r, const int* __restrict__ sq,
    const float* __restrict__ Eq, const float* __restrict__ Er,
    const float* __restrict__ att, const float* __restrict__ satt,
    const float* __restrict__ Wl2, const float* __restrict__ bl2,
    const float* __restrict__ Wl3, const float* __restrict__ bl3,
    float* __restrict__ xemb, float* __restrict__ shiftx,
    // fh
    const int* __restrict__ c,  const int* __restrict__ rg,
    const int* __restrict__ pc, const int* __restrict__ ac,
    const int* __restrict__ sc, const int* __restrict__ srg,
    const int* __restrict__ spc,const int* __restrict__ sac,
    const unsigned short* __restrict__ T16, const float* __restrict__ bpre,
    float* __restrict__ fh0, float* __restrict__ fh1)
{
    __shared__ float xs1[4][384];
    __shared__ float xs2[4][256];
    __shared__ float part[2][4][128];
    int b   = blockIdx.x;
    int tid = threadIdx.x;

    if (b < NB_PJ) {
        // ---- proj: 4 rows/block ----
        int r0 = b*4;
        for (int e = tid; e < 4*384; e += 256) {
            int i = e / 384, pos = e - i*384;
            int row = r0 + i;
            float v;
            if (pos < 128)      v = Eq[(size_t)q[row]*128 + pos];
            else if (pos < 256) v = Er[r[row]*128 + (pos-128)];
            else                v = att[row*128 + (pos-256)];
            xs1[i][pos] = v;
        }
        for (int e = tid; e < 4*256; e += 256) {
            int i = e >> 8, pos = e & 255;
            int row = r0 + i;
            xs2[i][pos] = (pos < 128) ? Eq[(size_t)sq[row]*128 + pos]
                                      : satt[row*128 + (pos-128)];
        }
        __syncthreads();

        int kg  = tid >> 7;
        int col = tid & 127;
        // l2: K=384, halves of 192
        {
            float acc[4];
            #pragma unroll
            for (int i = 0; i < 4; i++) acc[i] = 0.f;
            int k0 = kg*192;
            for (int kb = 0; kb < 192; kb += 8) {
                float wb[8];
                #pragma unroll
                for (int u = 0; u < 8; u++) wb[u] = Wl2[(k0+kb+u)*128 + col];
                #pragma unroll
                for (int u = 0; u < 8; u++) {
                    #pragma unroll
                    for (int i = 0; i < 4; i++) acc[i] += xs1[i][k0+kb+u]*wb[u];
                }
            }
            #pragma unroll
            for (int i = 0; i < 4; i++) part[kg][i][col] = acc[i];
        }
        __syncthreads();
        for (int e = tid; e < 512; e += 256) {
            int i = e >> 7, cc2 = e & 127;
            xemb[(r0+i)*128 + cc2] = bl2[cc2] + part[0][i][cc2] + part[1][i][cc2];
        }
        __syncthreads();
        // l3: K=256, halves of 128
        {
            float acc[4];
            #pragma unroll
            for (int i = 0; i < 4; i++) acc[i] = 0.f;
            int k0 = kg*128;
            for (int kb = 0; kb < 128; kb += 8) {
                float wb[8];
                #pragma unroll
                for (int u = 0; u < 8; u++) wb[u] = Wl3[(k0+kb+u)*128 + col];
                #pragma unroll
                for (int u = 0; u < 8; u++) {
                    #pragma unroll
                    for (int i = 0; i < 4; i++) acc[i] += xs2[i][k0+kb+u]*wb[u];
                }
            }
            #pragma unroll
            for (int i = 0; i < 4; i++) part[kg][i][col] = acc[i];
        }
        __syncthreads();
        for (int e = tid; e < 512; e += 256) {
            int i = e >> 7, cc2 = e & 127;
            shiftx[(r0+i)*128 + cc2] = bl3[cc2] + part[0][i][cc2] + part[1][i][cc2];
        }
        return;
    }
    // ---- fh: 2 tasks/block (128 threads each), bf16 T gather ----
    {
        int u     = (b - NB_PJ)*2 + (tid >> 7);   // 0..3199
        int which = u & 1;
        int row   = u >> 1;
        int t     = tid & 127;
        const int* C  = which ? sc  : c;
        const int* RG = which ? srg : rg;
        const int* PC = which ? spc : pc;
        const int* AC = which ? sac : ac;
        float* out = which ? fh1 : fh0;

        float acc = bpre[t];
        for (int m = 0; m < 4; m++) {
            int s = C[row*4 + m];
            if (s < 0) continue;
            int rgv = RG[row*4 + m];
            const unsigned short* Ts = T16 + (size_t)s*NT*128;
            #pragma unroll
            for (int f = 0; f < 4; f++) {
                int j1 = f*25 + rgv;
                int j2 = 100 + f*25 + PC[(row*4+m)*4 + f];
                int j3 = 200 + f*25 + AC[(row*4+m)*4 + f];
                acc += bf2f(Ts[j1*128 + t]) + bf2f(Ts[j2*128 + t]) + bf2f(Ts[j3*128 + t]);
            }
        }
        out[row*128 + t] = acc;
    }
}

// ===========================================================================
// LSTM with fused gates. grid (200, 2), 512 threads, ONE row per block.
// Thread owns gate col p = tid; whh col in 128 VGPRs (launch_bounds(512,2)
// caps at 256 VGPR so it FITS -- round-10's bare (512) spilled it to scratch,
// VGPR_Count=80). Recurrence inner product uses v_readlane (VALU) instead of
// 128 broadcast ds_reads/wave/step -- kills the shared-LDS-pipe bottleneck.
// ===========================================================================
__global__ void __launch_bounds__(512, 2) k_lstm(
    const float* __restrict__ xemb, const float* __restrict__ fh,
    const float* __restrict__ wT_in, const float* __restrict__ wT_fg,
    const float* __restrict__ whhT_in, const float* __restrict__ whhT_fg,
    const float* __restrict__ bih_in, const float* __restrict__ bhh_in,
    const float* __restrict__ bih_fg, const float* __restrict__ bhh_fg,
    float* __restrict__ h_in_out, float* __restrict__ h_fg_out)
{
    int which = blockIdx.y;
    const float* X  = which ? fh      : xemb;
    const float* WI = which ? wT_fg   : wT_in;
    const float* WH = which ? whhT_fg : whhT_in;
    const float* B1 = which ? bih_fg  : bih_in;
    const float* B2 = which ? bhh_fg  : bhh_in;
    float* OUT = which ? h_fg_out : h_in_out;

    int l0   = blockIdx.x;          // row 0..199
    int tid  = threadIdx.x;         // gate col p
    int lane = tid & 63;

    __shared__ float xr[8][128];   // x for all 8 steps
    __shared__ float gb[8][512];   // x-gates for all steps
    __shared__ float hL[128], csL[128], gl[512];

    for (int e = tid; e < 1024; e += 512) {
        int t = e >> 7, d = e & 127;
        xr[t][d] = X[(size_t)(t*200 + l0)*128 + d];
    }
    if (tid < 128) { hL[tid] = 0.f; csL[tid] = 0.f; }
    __syncthreads();

    // gates: gb[t][p] = bb + sum_k xr[t][k] * WI[k*512+p]
    float bb = B1[tid] + B2[tid];
    {
        float a[8];
        #pragma unroll
        for (int i = 0; i < 8; i++) a[i] = bb;
        for (int kb = 0; kb < 128; kb += 8) {
            float wv[8];
            #pragma unroll
            for (int u = 0; u < 8; u++) wv[u] = WI[(kb+u)*512 + tid];
            #pragma unroll
            for (int u = 0; u < 8; u++) {
                #pragma unroll
                for (int i = 0; i < 8; i++) a[i] += xr[i][kb+u]*wv[u];
            }
        }
        #pragma unroll
        for (int i = 0; i < 8; i++) gb[i][tid] = a[i];
    }

    // whh column -> registers (static indices, <=256 VGPR cap => real VGPRs)
    float w[128];
    #pragma unroll
    for (int k = 0; k < 128; k++) w[k] = WH[k*512 + tid];

    // recurrence: h broadcast via readlane (VALU), not LDS
    for (int t = 0; t < 8; t++) {
        float hlo = hL[lane];          // 2 coalesced ds_reads per wave
        float hhi = hL[lane + 64];
        float acc0 = gb[t][tid];       // own slot, no barrier needed
        float acc1 = 0.f;
        #pragma unroll
        for (int k = 0; k < 64; k++)
            acc0 += rdlane(hlo, k) * w[k];
        #pragma unroll
        for (int k = 0; k < 64; k++)
            acc1 += rdlane(hhi, k) * w[64 + k];
        gl[tid] = acc0 + acc1;
        __syncthreads();
        if (tid < 128) {
            float gi = gl[tid], gf = gl[128+tid], gg = gl[256+tid], go = gl[384+tid];
            float cn = sigf(gf)*csL[tid] + sigf(gi)*tanhf(gg);
            float hn = sigf(go)*tanhf(cn);
            csL[tid] = cn;
            hL[tid]  = hn;
            OUT[(size_t)(t*200 + l0)*128 + tid] = hn;
        }
        __syncthreads();
    }
}

// ===========================================================================
// FINAL: x1=relu([shiftx|h_in]@W4+b4); x2=relu([fh1|h_fg]@W5+b5);
// y=sigmoid([x1|x2]@W3+b3). 4 rows/block, 400 blocks, 256 thr.
// ===========================================================================
__global__ void __launch_bounds__(256) k_final(
    const float* __restrict__ shiftx, const float* __restrict__ h_in,
    const float* __restrict__ fh_shift, const float* __restrict__ h_fg,
    const float* __restrict__ Wfc4, const float* __restrict__ bfc4,
    const float* __restrict__ Wfc5, const float* __restrict__ bfc5,
    const float* __restrict__ Wfc3, const float* __restrict__ bfc3,
    float* __restrict__ out)
{
    int r0  = blockIdx.x * 4;
    int tid = threadIdx.x;
    int kg  = tid >> 7;
    int col = tid & 127;
    __shared__ float xa[4][256], xb[4][256];
    __shared__ float part[2][4][128];

    for (int e = tid; e < 4*256; e += 256) {
        int i = e >> 8, pos = e & 255;
        int row = r0 + i;
        xa[i][pos] = (pos < 128) ? shiftx[row*128 + pos]   : h_in[row*128 + pos-128];
        xb[i][pos] = (pos < 128) ? fh_shift[row*128 + pos] : h_fg[row*128 + pos-128];
    }
    __syncthreads();

    float acc4[4], acc5[4];
    #pragma unroll
    for (int i = 0; i < 4; i++) { acc4[i] = 0.f; acc5[i] = 0.f; }
    int k0 = kg * 128;
    for (int kb = 0; kb < 128; kb += 8) {
        float w4[8], w5[8];
        #pragma unroll
        for (int u = 0; u < 8; u++) {
            w4[u] = Wfc4[(k0+kb+u)*128 + col];
            w5[u] = Wfc5[(k0+kb+u)*128 + col];
        }
        #pragma unroll
        for (int u = 0; u < 8; u++) {
            int k = k0 + kb + u;
            #pragma unroll
            for (int i = 0; i < 4; i++) {
                acc4[i] += xa[i][k] * w4[u];
                acc5[i] += xb[i][k] * w5[u];
            }
        }
    }

    #pragma unroll
    for (int i = 0; i < 4; i++) part[kg][i][col] = acc4[i];
    __syncthreads();
    float x1r[2];
    #pragma unroll
    for (int j = 0; j < 2; j++) {
        int e = tid + 256*j;
        int i = e >> 7, cc2 = e & 127;
        x1r[j] = fmaxf(part[0][i][cc2] + part[1][i][cc2] + bfc4[cc2], 0.f);
    }
    __syncthreads();
    #pragma unroll
    for (int i = 0; i < 4; i++) part[kg][i][col] = acc5[i];
    __syncthreads();
    float x2r[2];
    #pragma unroll
    for (int j = 0; j < 2; j++) {
        int e = tid + 256*j;
        int i = e >> 7, cc2 = e & 127;
        x2r[j] = fmaxf(part[0][i][cc2] + part[1][i][cc2] + bfc5[cc2], 0.f);
    }
    __syncthreads();

    // fc3 contributions; reuse part[0] as cont[4][128]
    float* cont = &part[0][0][0];
    #pragma unroll
    for (int j = 0; j < 2; j++) {
        int e = tid + 256*j;
        int i = e >> 7, cc2 = e & 127;
        cont[i*128 + cc2] = x1r[j]*Wfc3[cc2] + x2r[j]*Wfc3[128 + cc2];
    }
    __syncthreads();
    int wv = tid >> 6, lane = tid & 63;      // wave wv handles row wv
    float sum = cont[wv*128 + lane] + cont[wv*128 + lane + 64];
    #pragma unroll
    for (int off = 32; off > 0; off >>= 1) sum += __shfl_xor(sum, off);
    if (lane == 0) out[r0 + wv] = 1.f/(1.f + expf(-(sum + bfc3[0])));
}

// ---------------------------------------------------------------------------
extern "C" void kernel_launch(void* const* d_in, const int* in_sizes, int n_in,
                              void* d_out, int out_size, void* d_ws, size_t ws_size,
                              hipStream_t stream)
{
    const int*   q      = (const int*)d_in[0];
    const int*   c      = (const int*)d_in[1];
    const int*   sq     = (const int*)d_in[2];
    const int*   sc     = (const int*)d_in[3];
    const int*   r      = (const int*)d_in[4];
    const int*   rg     = (const int*)d_in[5];
    const int*   pc     = (const int*)d_in[6];
    const int*   ac     = (const int*)d_in[7];
    const int*   srg    = (const int*)d_in[8];
    const int*   spc    = (const int*)d_in[9];
    const int*   sac    = (const int*)d_in[10];
    const float* Es     = (const float*)d_in[11];
    const float* Eq     = (const float*)d_in[12];
    const float* Er     = (const float*)d_in[13];
    const float* wih_in = (const float*)d_in[14];
    const float* whh_in = (const float*)d_in[15];
    const float* bih_in = (const float*)d_in[16];
    const float* bhh_in = (const float*)d_in[17];
    const float* wih_fg = (const float*)d_in[18];
    const float* whh_fg = (const float*)d_in[19];
    const float* bih_fg = (const float*)d_in[20];
    const float* bhh_fg = (const float*)d_in[21];
    const float* Wl2    = (const float*)d_in[22];
    const float* bl2    = (const float*)d_in[23];
    const float* Wl3    = (const float*)d_in[24];
    const float* bl3    = (const float*)d_in[25];
    const float* Wfc3   = (const float*)d_in[26];
    const float* bfc3   = (const float*)d_in[27];
    const float* Wfc4   = (const float*)d_in[28];
    const float* bfc4   = (const float*)d_in[29];
    const float* Wfc5   = (const float*)d_in[30];
    const float* bfc5   = (const float*)d_in[31];
    const float* Wc     = (const float*)d_in[32];
    const float* Wp     = (const float*)d_in[33];
    const float* bpre   = (const float*)d_in[34];

    float* W = (float*)d_ws;
    unsigned short* T16 = (unsigned short*)W;  W += 100*NT*128/2;   // bf16 T: 7.68 MB
    float* att     = W;  W += ROWS*128;
    float* satt    = W;  W += ROWS*128;
    float* xemb    = W;  W += ROWS*128;
    float* shiftx  = W;  W += ROWS*128;
    float* fh0     = W;  W += ROWS*128;
    float* fh1     = W;  W += ROWS*128;
    float* wT_in   = W;  W += 512*128;
    float* wT_fg   = W;  W += 512*128;
    float* whhT_in = W;  W += 512*128;
    float* whhT_fg = W;  W += 512*128;
    float* h_in    = W;  W += ROWS*128;
    float* h_fg    = W;  W += ROWS*128;

    hipLaunchKernelGGL(k_stage1, dim3(NB_TR + NB_TP + NB_AT), dim3(256), 0, stream,
        wih_in, wih_fg, whh_in, whh_fg, wT_in, wT_fg, whhT_in, whhT_fg,
        Es, Wc, Wp, T16,
        q, c, sq, sc, Eq, att, satt);

    hipLaunchKernelGGL(k_stage2, dim3(NB_PJ + NB_FH), dim3(256), 0, stream,
        q, r, sq, Eq, Er, att, satt, Wl2, bl2, Wl3, bl3, xemb, shiftx,
        c, rg, pc, ac, sc, srg, spc, sac, T16, bpre, fh0, fh1);

    hipLaunchKernelGGL(k_lstm, dim3(200, 2), dim3(512), 0, stream,
        xemb, fh0, wT_in, wT_fg, whhT_in, whhT_fg,
        bih_in, bhh_in, bih_fg, bhh_fg, h_in, h_fg);

    hipLaunchKernelGGL(k_final, dim3(400), dim3(256), 0, stream,
        shiftx, h_in, fh1, h_fg, Wfc4, bfc4, Wfc5, bfc5, Wfc3, bfc3, (float*)d_out);
}